// Round 1
// baseline (272.970 us; speedup 1.0000x reference)
//
#include <hip/hip_runtime.h>
#include <hip/hip_bf16.h>

#define CIN   128
#define COUT  256
#define BATCH 16
#define HH    64
#define WW    64
#define TH    32
#define TW    32
#define NT    (BATCH*TH*TW)   /* 16384 winograd tiles */

typedef __bf16 bf16x8 __attribute__((ext_vector_type(8)));
typedef float  f32x4  __attribute__((ext_vector_type(4)));

// ---------------------------------------------------------------------------
// Kernel 1: weight transform  U[pq][k][c] = (G w G^T)[p][q], bf16
// ---------------------------------------------------------------------------
__global__ __launch_bounds__(256) void wg_wtrans(const float* __restrict__ w,
                                                 __hip_bfloat16* __restrict__ U) {
    int idx = blockIdx.x * 256 + threadIdx.x;       // idx = k*CIN + c
    if (idx >= COUT * CIN) return;
    const float* wp = w + idx * 9;
    float g[3][3];
#pragma unroll
    for (int x = 0; x < 3; x++)
#pragma unroll
        for (int y = 0; y < 3; y++) g[x][y] = wp[x * 3 + y];

    // t = G * g  (4x3)
    float t[4][3];
#pragma unroll
    for (int y = 0; y < 3; y++) {
        t[0][y] = g[0][y];
        t[1][y] = 0.5f * (g[0][y] + g[1][y] + g[2][y]);
        t[2][y] = 0.5f * (g[0][y] - g[1][y] + g[2][y]);
        t[3][y] = g[2][y];
    }
    // u = t * G^T (4x4)
#pragma unroll
    for (int p = 0; p < 4; p++) {
        float u0 = t[p][0];
        float u1 = 0.5f * (t[p][0] + t[p][1] + t[p][2]);
        float u2 = 0.5f * (t[p][0] - t[p][1] + t[p][2]);
        float u3 = t[p][2];
        U[(p * 4 + 0) * (COUT * CIN) + idx] = __float2bfloat16(u0);
        U[(p * 4 + 1) * (COUT * CIN) + idx] = __float2bfloat16(u1);
        U[(p * 4 + 2) * (COUT * CIN) + idx] = __float2bfloat16(u2);
        U[(p * 4 + 3) * (COUT * CIN) + idx] = __float2bfloat16(u3);
    }
}

// ---------------------------------------------------------------------------
// Kernel 2: input transform  V[pq][bij][c] = (BT d BT^T)[p][q], bf16
// One block: fixed (b, i), 32 channels, all 32 j-tiles. X staged via LDS.
// LDS layout: per channel 265 floats = 4 rows * 66 cols (x=-1..64) + 1 pad
// (odd stride -> conflict-free across the 32 c-lanes).
// ---------------------------------------------------------------------------
__global__ __launch_bounds__(1024) void wg_itrans(const float* __restrict__ X,
                                                  __hip_bfloat16* __restrict__ V) {
    __shared__ float lds[32 * 265];
    const int c0 = blockIdx.x * 32;
    const int i  = blockIdx.y;
    const int b  = blockIdx.z;
    const int tid = threadIdx.x;

    // zero the x=-1 and x=64 border columns
    for (int t = tid; t < 32 * 4; t += 1024) {
        int cc = t >> 2, r = t & 3;
        lds[cc * 265 + r * 66 + 0]  = 0.f;
        lds[cc * 265 + r * 66 + 65] = 0.f;
    }
    // main rows: y = 2i-1+r, coalesced in x
    for (int t = tid; t < 32 * 4 * 64; t += 1024) {
        int x = t & 63, r = (t >> 6) & 3, cc = t >> 8;
        int y = 2 * i - 1 + r;
        float v = 0.f;
        if (y >= 0 && y < HH) v = X[(((b * CIN) + (c0 + cc)) * HH + y) * WW + x];
        lds[cc * 265 + r * 66 + 1 + x] = v;
    }
    __syncthreads();

    const int c = tid & 31;
    const int j = tid >> 5;
    const float* base = &lds[c * 265 + 2 * j];   // (r, dx) at base[r*66 + dx]

    float t0[4], t1[4], t2[4], t3[4];
#pragma unroll
    for (int y = 0; y < 4; y++) {
        float a  = base[0 * 66 + y];
        float bb = base[1 * 66 + y];
        float cc = base[2 * 66 + y];
        float dd = base[3 * 66 + y];
        t0[y] = a - cc;
        t1[y] = bb + cc;
        t2[y] = cc - bb;
        t3[y] = bb - dd;
    }
    float vm[4][4];
#pragma unroll
    for (int p = 0; p < 4; p++) {
        const float* tp = (p == 0) ? t0 : (p == 1) ? t1 : (p == 2) ? t2 : t3;
        vm[p][0] = tp[0] - tp[2];
        vm[p][1] = tp[1] + tp[2];
        vm[p][2] = tp[2] - tp[1];
        vm[p][3] = tp[1] - tp[3];
    }

    const int bij = b * (TH * TW) + i * TW + j;
    const int vo  = bij * CIN + (c0 + c);
#pragma unroll
    for (int p = 0; p < 4; p++)
#pragma unroll
        for (int q = 0; q < 4; q++)
            V[(p * 4 + q) * (NT * CIN) + vo] = __float2bfloat16(vm[p][q]);
}

// ---------------------------------------------------------------------------
// Kernel 3: 16 per-pq GEMMs (M=kout=256, N=bij=16384, K=cin=128) fused with
// the AT * Y * AT^T output transform + bias.
// Block = 4 waves (2m x 2n of 16x16 frags) -> 32x32 tile. Grid = 8 x 512.
// A = U[pq][m=kout][k=c] (row-major, k contiguous)
// B = V[pq][n=bij ][k=c] (row-major, k contiguous)  -> B[k][n] fragment reads
// lane l: A row / B col = l&15, k = 8*(l>>4)+j (contiguous 16B loads)
// D: col = l&15 (bij), row = (l>>4)*4 + reg (kout)
// ---------------------------------------------------------------------------
__global__ __launch_bounds__(256) void wg_gemm(const __hip_bfloat16* __restrict__ U,
                                               const __hip_bfloat16* __restrict__ V,
                                               const float* __restrict__ bias,
                                               float* __restrict__ out) {
    // bijective XCD swizzle: the 8 m-tiles of one n-tile land on one XCD
    int orig = blockIdx.x;                   // 0..4095
    int wg   = (orig & 7) * 512 + (orig >> 3);
    int mt   = wg & 7;                       // kout tile (8 x 32)
    int nt   = wg >> 3;                      // bij  tile (512 x 32)

    const int wave = threadIdx.x >> 6;
    const int lane = threadIdx.x & 63;
    const int wm = wave >> 1, wn = wave & 1;
    const int lr = lane & 15, kb = lane >> 4;

    const int m0 = mt * 32 + wm * 16;        // kout base
    const int n0 = nt * 32 + wn * 16;        // bij base

    f32x4 acc[16];
#pragma unroll
    for (int p = 0; p < 16; p++) acc[p] = (f32x4){0.f, 0.f, 0.f, 0.f};

    const __hip_bfloat16* ap0 = U + (m0 + lr) * CIN + kb * 8;
    const __hip_bfloat16* bp0 = V + (size_t)(n0 + lr) * CIN + kb * 8;

    for (int cc = 0; cc < CIN; cc += 32) {
#pragma unroll
        for (int pq = 0; pq < 16; pq++) {
            bf16x8 a = *reinterpret_cast<const bf16x8*>(ap0 + pq * (COUT * CIN) + cc);
            bf16x8 b = *reinterpret_cast<const bf16x8*>(bp0 + (size_t)pq * (NT * CIN) + cc);
            acc[pq] = __builtin_amdgcn_mfma_f32_16x16x32_bf16(a, b, acc[pq], 0, 0, 0);
        }
    }

    // epilogue: per reg r, Y[p][q] = acc[p*4+q][r]; out2x2 = AT Y AT^T + bias
    const int bij = n0 + lr;
    const int bb = bij >> 10, ti = (bij >> 5) & 31, tj = bij & 31;
#pragma unroll
    for (int r = 0; r < 4; r++) {
        const int kch = m0 + kb * 4 + r;
        float Y[4][4];
#pragma unroll
        for (int p = 0; p < 4; p++)
#pragma unroll
            for (int q = 0; q < 4; q++) Y[p][q] = acc[p * 4 + q][r];

        float ta[4], tb[4];
#pragma unroll
        for (int q = 0; q < 4; q++) {
            ta[q] = Y[0][q] + Y[1][q] + Y[2][q];
            tb[q] = Y[1][q] - Y[2][q] - Y[3][q];
        }
        const float bv = bias[kch];
        float o00 = ta[0] + ta[1] + ta[2] + bv;
        float o01 = ta[1] - ta[2] - ta[3] + bv;
        float o10 = tb[0] + tb[1] + tb[2] + bv;
        float o11 = tb[1] - tb[2] - tb[3] + bv;

        float* op = out + (((size_t)bb * COUT + kch) * HH + 2 * ti) * WW + 2 * tj;
        *reinterpret_cast<float2*>(op)      = make_float2(o00, o01);
        *reinterpret_cast<float2*>(op + WW) = make_float2(o10, o11);
    }
}

// ---------------------------------------------------------------------------
extern "C" void kernel_launch(void* const* d_in, const int* in_sizes, int n_in,
                              void* d_out, int out_size, void* d_ws, size_t ws_size,
                              hipStream_t stream) {
    const float* X    = (const float*)d_in[0];
    const float* w    = (const float*)d_in[1];
    const float* bias = (const float*)d_in[2];
    float* out        = (float*)d_out;

    __hip_bfloat16* U = (__hip_bfloat16*)d_ws;                       // 1 MB
    __hip_bfloat16* V = (__hip_bfloat16*)((char*)d_ws + (1u << 20)); // 64 MB

    wg_wtrans<<<(COUT * CIN + 255) / 256, 256, 0, stream>>>(w, U);
    wg_itrans<<<dim3(CIN / 32, TH, BATCH), 1024, 0, stream>>>(X, V);
    wg_gemm<<<(COUT / 32) * (NT / 32), 256, 0, stream>>>(U, V, bias, out);
}

// Round 2
// 121.407 us; speedup vs baseline: 2.2484x; 2.2484x over previous
//
#include <hip/hip_runtime.h>
#include <hip/hip_bf16.h>

#define CIN   128
#define COUT  256
#define BATCH 16
#define HH    64
#define WW    64
#define TH    32
#define TW    32
#define NT    (BATCH*TH*TW)   /* 16384 winograd tiles */

typedef __bf16 bf16x8 __attribute__((ext_vector_type(8)));
typedef float  f32x4  __attribute__((ext_vector_type(4)));

// ---------------------------------------------------------------------------
// Kernel 1: weight transform  U[pq][k][c] = (G w G^T)[p][q], bf16
// ---------------------------------------------------------------------------
__global__ __launch_bounds__(256) void wg_wtrans(const float* __restrict__ w,
                                                 __hip_bfloat16* __restrict__ U) {
    int idx = blockIdx.x * 256 + threadIdx.x;       // idx = k*CIN + c
    if (idx >= COUT * CIN) return;
    const float* wp = w + idx * 9;
    float g[3][3];
#pragma unroll
    for (int x = 0; x < 3; x++)
#pragma unroll
        for (int y = 0; y < 3; y++) g[x][y] = wp[x * 3 + y];

    float t[4][3];
#pragma unroll
    for (int y = 0; y < 3; y++) {
        t[0][y] = g[0][y];
        t[1][y] = 0.5f * (g[0][y] + g[1][y] + g[2][y]);
        t[2][y] = 0.5f * (g[0][y] - g[1][y] + g[2][y]);
        t[3][y] = g[2][y];
    }
#pragma unroll
    for (int p = 0; p < 4; p++) {
        float u0 = t[p][0];
        float u1 = 0.5f * (t[p][0] + t[p][1] + t[p][2]);
        float u2 = 0.5f * (t[p][0] - t[p][1] + t[p][2]);
        float u3 = t[p][2];
        U[(p * 4 + 0) * (COUT * CIN) + idx] = __float2bfloat16(u0);
        U[(p * 4 + 1) * (COUT * CIN) + idx] = __float2bfloat16(u1);
        U[(p * 4 + 2) * (COUT * CIN) + idx] = __float2bfloat16(u2);
        U[(p * 4 + 3) * (COUT * CIN) + idx] = __float2bfloat16(u3);
    }
}

// ---------------------------------------------------------------------------
// Kernel 2: input transform  V[pq][bij][c] = (BT d BT^T)[p][q], bf16
// ---------------------------------------------------------------------------
__global__ __launch_bounds__(1024) void wg_itrans(const float* __restrict__ X,
                                                  __hip_bfloat16* __restrict__ V) {
    __shared__ float lds[32 * 265];
    const int c0 = blockIdx.x * 32;
    const int i  = blockIdx.y;
    const int b  = blockIdx.z;
    const int tid = threadIdx.x;

    for (int t = tid; t < 32 * 4; t += 1024) {
        int cc = t >> 2, r = t & 3;
        lds[cc * 265 + r * 66 + 0]  = 0.f;
        lds[cc * 265 + r * 66 + 65] = 0.f;
    }
    for (int t = tid; t < 32 * 4 * 64; t += 1024) {
        int x = t & 63, r = (t >> 6) & 3, cc = t >> 8;
        int y = 2 * i - 1 + r;
        float v = 0.f;
        if (y >= 0 && y < HH) v = X[(((b * CIN) + (c0 + cc)) * HH + y) * WW + x];
        lds[cc * 265 + r * 66 + 1 + x] = v;
    }
    __syncthreads();

    const int c = tid & 31;
    const int j = tid >> 5;
    const float* base = &lds[c * 265 + 2 * j];

    float t0[4], t1[4], t2[4], t3[4];
#pragma unroll
    for (int y = 0; y < 4; y++) {
        float a  = base[0 * 66 + y];
        float bb = base[1 * 66 + y];
        float cc = base[2 * 66 + y];
        float dd = base[3 * 66 + y];
        t0[y] = a - cc;
        t1[y] = bb + cc;
        t2[y] = cc - bb;
        t3[y] = bb - dd;
    }
    float vm[4][4];
#pragma unroll
    for (int p = 0; p < 4; p++) {
        const float* tp = (p == 0) ? t0 : (p == 1) ? t1 : (p == 2) ? t2 : t3;
        vm[p][0] = tp[0] - tp[2];
        vm[p][1] = tp[1] + tp[2];
        vm[p][2] = tp[2] - tp[1];
        vm[p][3] = tp[1] - tp[3];
    }

    const int bij = b * (TH * TW) + i * TW + j;
    const int vo  = bij * CIN + (c0 + c);
#pragma unroll
    for (int p = 0; p < 4; p++)
#pragma unroll
        for (int q = 0; q < 4; q++)
            V[(p * 4 + q) * (NT * CIN) + vo] = __float2bfloat16(vm[p][q]);
}

// ---------------------------------------------------------------------------
// Kernel 3: pq-split GEMM. Block = 16 waves (1024 thr); wave w owns the
// pq=w GEMM over a 64x64 (kout x bij) tile: 4x4 frags of 16x16x32 bf16,
// K=128 fully unrolled, fragments loaded straight from global (L2).
// Epilogue: cross-wave AT*Y*AT^T via LDS in 8 chunks of
// [16 pq][32 bij][16 kout] f32 (row stride 20 -> aligned b128 writes).
// ---------------------------------------------------------------------------
#define RS    20
#define PLANE (32*RS)          /* 640 floats per pq plane */

__global__ __launch_bounds__(1024) void wg_gemm2(const __hip_bfloat16* __restrict__ U,
                                                 const __hip_bfloat16* __restrict__ V,
                                                 const float* __restrict__ bias,
                                                 float* __restrict__ out) {
    __shared__ float smem[16 * PLANE];   // 40 KB

    // bijective XCD swizzle: 4 mt-blocks of one nt run on the same XCD
    int orig = blockIdx.x;               // 0..1023
    int wg   = (orig & 7) * 128 + (orig >> 3);
    int mt   = wg & 3;                   // kout tile (4 x 64)
    int nt   = wg >> 2;                  // bij  tile (256 x 64)
    const int m0 = mt * 64, n0 = nt * 64;

    const int tid  = threadIdx.x;
    const int wave = tid >> 6;           // = pq
    const int lane = tid & 63;
    const int lr = lane & 15, kb = lane >> 4;

    const __hip_bfloat16* Apq = U + (size_t)wave * (COUT * CIN);
    const __hip_bfloat16* Bpq = V + (size_t)wave * (NT * CIN);

    const __hip_bfloat16* ap[4];
    const __hip_bfloat16* bp[4];
#pragma unroll
    for (int mi = 0; mi < 4; mi++) ap[mi] = Apq + (m0 + mi * 16 + lr) * CIN + kb * 8;
#pragma unroll
    for (int ni = 0; ni < 4; ni++) bp[ni] = Bpq + (size_t)(n0 + ni * 16 + lr) * CIN + kb * 8;

    f32x4 acc[4][4];
#pragma unroll
    for (int mi = 0; mi < 4; mi++)
#pragma unroll
        for (int ni = 0; ni < 4; ni++) acc[mi][ni] = (f32x4){0.f, 0.f, 0.f, 0.f};

#pragma unroll
    for (int cc = 0; cc < CIN; cc += 32) {
        bf16x8 a[4], b[4];
#pragma unroll
        for (int mi = 0; mi < 4; mi++) a[mi] = *reinterpret_cast<const bf16x8*>(ap[mi] + cc);
#pragma unroll
        for (int ni = 0; ni < 4; ni++) b[ni] = *reinterpret_cast<const bf16x8*>(bp[ni] + cc);
#pragma unroll
        for (int mi = 0; mi < 4; mi++)
#pragma unroll
            for (int ni = 0; ni < 4; ni++)
                acc[mi][ni] = __builtin_amdgcn_mfma_f32_16x16x32_bf16(a[mi], b[ni], acc[mi][ni], 0, 0, 0);
    }

    // ---- epilogue: 8 chunks (mi, nh): [16 pq][32 bij][16 kout] in LDS ----
    const int col = tid & 31;            // bij within chunk (read phase)
    const int row = (tid >> 5) & 15;     // kout row within frag (read phase)
    float* plane = smem + wave * PLANE;

#pragma unroll
    for (int mi = 0; mi < 4; mi++) {
#pragma unroll
        for (int nh = 0; nh < 2; nh++) {
            __syncthreads();             // previous chunk's reads complete
            // write: 2 frags (ni = nh*2+nj), b128 per frag
#pragma unroll
            for (int nj = 0; nj < 2; nj++) {
                int ni = nh * 2 + nj;
                *reinterpret_cast<f32x4*>(&plane[(nj * 16 + lr) * RS + kb * 4]) = acc[mi][ni];
            }
            __syncthreads();
            if (tid < 512) {
                float y[16];
#pragma unroll
                for (int pq = 0; pq < 16; pq++)
                    y[pq] = smem[pq * PLANE + col * RS + row];

                float ta[4], tb[4];
#pragma unroll
                for (int q = 0; q < 4; q++) {
                    ta[q] = y[0 * 4 + q] + y[1 * 4 + q] + y[2 * 4 + q];
                    tb[q] = y[1 * 4 + q] - y[2 * 4 + q] - y[3 * 4 + q];
                }
                const int kch = m0 + mi * 16 + row;
                const int bij = n0 + nh * 32 + col;
                const float bv = bias[kch];
                float o00 = ta[0] + ta[1] + ta[2] + bv;
                float o01 = ta[1] - ta[2] - ta[3] + bv;
                float o10 = tb[0] + tb[1] + tb[2] + bv;
                float o11 = tb[1] - tb[2] - tb[3] + bv;

                const int bb = bij >> 10, ti = (bij >> 5) & 31, tj = bij & 31;
                float* op = out + (((size_t)bb * COUT + kch) * HH + 2 * ti) * WW + 2 * tj;
                *reinterpret_cast<float2*>(op)      = make_float2(o00, o01);
                *reinterpret_cast<float2*>(op + WW) = make_float2(o10, o11);
            }
        }
    }
}

// ---------------------------------------------------------------------------
extern "C" void kernel_launch(void* const* d_in, const int* in_sizes, int n_in,
                              void* d_out, int out_size, void* d_ws, size_t ws_size,
                              hipStream_t stream) {
    const float* X    = (const float*)d_in[0];
    const float* w    = (const float*)d_in[1];
    const float* bias = (const float*)d_in[2];
    float* out        = (float*)d_out;

    __hip_bfloat16* U = (__hip_bfloat16*)d_ws;                       // 1 MB
    __hip_bfloat16* V = (__hip_bfloat16*)((char*)d_ws + (1u << 20)); // 64 MB

    wg_wtrans<<<(COUT * CIN + 255) / 256, 256, 0, stream>>>(w, U);
    wg_itrans<<<dim3(CIN / 32, TH, BATCH), 1024, 0, stream>>>(X, V);
    wg_gemm2<<<(COUT / 64) * (NT / 64), 1024, 0, stream>>>(U, V, bias, out);
}

// Round 3
// 88.895 us; speedup vs baseline: 3.0707x; 1.3657x over previous
//
#include <hip/hip_runtime.h>
#include <hip/hip_bf16.h>
#include <cstdint>

#define CIN   128
#define COUT  256
#define BATCH 16
#define HH    64
#define WW    64
#define TH    32
#define TW    32
#define NT    (BATCH*TH*TW)   /* 16384 winograd tiles */
#define APQ   (COUT*CIN)      /* U plane: 32768 elems */
#define BPQ   (NT*CIN)        /* V plane: 2097152 elems */

typedef __bf16 bf16x8 __attribute__((ext_vector_type(8)));
typedef float  f32x4  __attribute__((ext_vector_type(4)));

__device__ __forceinline__ void gload16(const void* g, void* l) {
    __builtin_amdgcn_global_load_lds(
        (const __attribute__((address_space(1))) uint32_t*)g,
        (__attribute__((address_space(3))) uint32_t*)l, 16, 0, 0);
}

// ---------------------------------------------------------------------------
// Kernel 1: weight transform  U[pq][k][c] = (G w G^T)[p][q], bf16
// ---------------------------------------------------------------------------
__global__ __launch_bounds__(256) void wg_wtrans(const float* __restrict__ w,
                                                 __hip_bfloat16* __restrict__ U) {
    int idx = blockIdx.x * 256 + threadIdx.x;       // idx = k*CIN + c
    if (idx >= COUT * CIN) return;
    const float* wp = w + idx * 9;
    float g[3][3];
#pragma unroll
    for (int x = 0; x < 3; x++)
#pragma unroll
        for (int y = 0; y < 3; y++) g[x][y] = wp[x * 3 + y];

    float t[4][3];
#pragma unroll
    for (int y = 0; y < 3; y++) {
        t[0][y] = g[0][y];
        t[1][y] = 0.5f * (g[0][y] + g[1][y] + g[2][y]);
        t[2][y] = 0.5f * (g[0][y] - g[1][y] + g[2][y]);
        t[3][y] = g[2][y];
    }
#pragma unroll
    for (int p = 0; p < 4; p++) {
        float u0 = t[p][0];
        float u1 = 0.5f * (t[p][0] + t[p][1] + t[p][2]);
        float u2 = 0.5f * (t[p][0] - t[p][1] + t[p][2]);
        float u3 = t[p][2];
        U[(p * 4 + 0) * APQ + idx] = __float2bfloat16(u0);
        U[(p * 4 + 1) * APQ + idx] = __float2bfloat16(u1);
        U[(p * 4 + 2) * APQ + idx] = __float2bfloat16(u2);
        U[(p * 4 + 3) * APQ + idx] = __float2bfloat16(u3);
    }
}

// ---------------------------------------------------------------------------
// Kernel 2: input transform  V[pq][bij][c] = (BT d BT^T)[p][q], bf16
// ---------------------------------------------------------------------------
__global__ __launch_bounds__(1024) void wg_itrans(const float* __restrict__ X,
                                                  __hip_bfloat16* __restrict__ V) {
    __shared__ float lds[32 * 265];
    const int c0 = blockIdx.x * 32;
    const int i  = blockIdx.y;
    const int b  = blockIdx.z;
    const int tid = threadIdx.x;

    for (int t = tid; t < 32 * 4; t += 1024) {
        int cc = t >> 2, r = t & 3;
        lds[cc * 265 + r * 66 + 0]  = 0.f;
        lds[cc * 265 + r * 66 + 65] = 0.f;
    }
    for (int t = tid; t < 32 * 4 * 64; t += 1024) {
        int x = t & 63, r = (t >> 6) & 3, cc = t >> 8;
        int y = 2 * i - 1 + r;
        float v = 0.f;
        if (y >= 0 && y < HH) v = X[(((b * CIN) + (c0 + cc)) * HH + y) * WW + x];
        lds[cc * 265 + r * 66 + 1 + x] = v;
    }
    __syncthreads();

    const int c = tid & 31;
    const int j = tid >> 5;
    const float* base = &lds[c * 265 + 2 * j];

    float t0[4], t1[4], t2[4], t3[4];
#pragma unroll
    for (int y = 0; y < 4; y++) {
        float a  = base[0 * 66 + y];
        float bb = base[1 * 66 + y];
        float cc = base[2 * 66 + y];
        float dd = base[3 * 66 + y];
        t0[y] = a - cc;
        t1[y] = bb + cc;
        t2[y] = cc - bb;
        t3[y] = bb - dd;
    }
    float vm[4][4];
#pragma unroll
    for (int p = 0; p < 4; p++) {
        const float* tp = (p == 0) ? t0 : (p == 1) ? t1 : (p == 2) ? t2 : t3;
        vm[p][0] = tp[0] - tp[2];
        vm[p][1] = tp[1] + tp[2];
        vm[p][2] = tp[2] - tp[1];
        vm[p][3] = tp[1] - tp[3];
    }

    const int bij = b * (TH * TW) + i * TW + j;
    const int vo  = bij * CIN + (c0 + c);
#pragma unroll
    for (int p = 0; p < 4; p++)
#pragma unroll
        for (int q = 0; q < 4; q++)
            V[(size_t)(p * 4 + q) * BPQ + vo] = __float2bfloat16(vm[p][q]);
}

// ---------------------------------------------------------------------------
// Kernel 3: fused GEMM + output transform.
// Block [128 kout x 64 bij], 4 waves (2m x 2n), wave tile 64x32 (4x2 frags).
// K-loop: 16 pq x 4 k-steps (BK=32), LDS double-buffered via global_load_lds,
// fragment-major LDS layout (lane-linear ds_read_b128, zero bank conflicts).
// Per-pq fold into 4 register Y-planes with compile-time AT weights.
// ---------------------------------------------------------------------------
__global__ __launch_bounds__(256, 2) void wg_gemm3(const __hip_bfloat16* __restrict__ U,
                                                   const __hip_bfloat16* __restrict__ V,
                                                   const float* __restrict__ bias,
                                                   float* __restrict__ out) {
    __shared__ char lds[2 * 12288];      // per buf: A 8192B (128x32), B 4096B (64x32)

    // bijective XCD swizzle (512 % 8 == 0): 64 consecutive wg per XCD
    int orig = blockIdx.x;
    int wg   = (orig & 7) * 64 + (orig >> 3);
    const int mt = wg & 1, nt = wg >> 1;
    const int m0 = mt * 128, n0 = nt * 64;

    const int tid  = threadIdx.x;
    const int lane = tid & 63;
    const int wave = tid >> 6;
    const int wm = wave >> 1, wn = wave & 1;

    // staging thread-constants: chunk c -> frag=c>>6, kb=(c>>4)&3, lr=c&15
    const int kcol  = ((tid >> 4) & 3) * 8;
    const int arow0 = (tid >> 6) * 16 + (tid & 15);
    const int brow  = ((tid >> 6) & 3) * 16 + (tid & 15);
    const __hip_bfloat16* pa0 = U + (m0 + arow0) * CIN + kcol;
    const __hip_bfloat16* pa1 = U + (m0 + 64 + arow0) * CIN + kcol;
    const __hip_bfloat16* pb  = V + (size_t)(n0 + brow) * CIN + kcol;

    const int ldsA0 = wave * 1024;
    const int ldsA1 = 4096 + wave * 1024;
    const int ldsB  = 8192 + wave * 1024;

    auto stage = [&](int t, int buf) {
        const int pq = t >> 2, kk = t & 3;
        char* base = lds + buf * 12288;
        gload16(pa0 + pq * APQ + kk * 32, base + ldsA0);
        gload16(pa1 + pq * APQ + kk * 32, base + ldsA1);
        gload16(pb + (size_t)pq * BPQ + kk * 32, base + ldsB);
    };

    f32x4 yac[2][2][4][2];               // [x][y][mi][nj] = 128 VGPR
#pragma unroll
    for (int x = 0; x < 2; x++)
#pragma unroll
        for (int y = 0; y < 2; y++)
#pragma unroll
            for (int mi = 0; mi < 4; mi++)
#pragma unroll
                for (int nj = 0; nj < 2; nj++) yac[x][y][mi][nj] = (f32x4){0.f, 0.f, 0.f, 0.f};
    f32x4 mac[4][2];
    const f32x4 fz = (f32x4){0.f, 0.f, 0.f, 0.f};

    stage(0, 0);
    __syncthreads();

#pragma unroll
    for (int t = 0; t < 64; ++t) {
        const int pq = t >> 2, kk = t & 3, cur = t & 1;
        if (t < 63) stage(t + 1, cur ^ 1);

        const char* base = lds + cur * 12288;
        bf16x8 av[4], bv[2];
#pragma unroll
        for (int mi = 0; mi < 4; mi++)
            av[mi] = *reinterpret_cast<const bf16x8*>(base + ((wm * 4 + mi) * 64 + lane) * 16);
#pragma unroll
        for (int nj = 0; nj < 2; nj++)
            bv[nj] = *reinterpret_cast<const bf16x8*>(base + 8192 + ((wn * 2 + nj) * 64 + lane) * 16);

#pragma unroll
        for (int mi = 0; mi < 4; mi++)
#pragma unroll
            for (int nj = 0; nj < 2; nj++)
                mac[mi][nj] = __builtin_amdgcn_mfma_f32_16x16x32_bf16(
                    av[mi], bv[nj], (kk == 0) ? fz : mac[mi][nj], 0, 0, 0);

        if (kk == 3) {                   // fold M[pq] into Y with AT weights
            const int p = pq >> 2, q = pq & 3;
            constexpr float W0[4] = {1.f, 1.f, 1.f, 0.f};
            constexpr float W1[4] = {0.f, 1.f, -1.f, -1.f};
            const float w00 = W0[p] * W0[q], w01 = W0[p] * W1[q];
            const float w10 = W1[p] * W0[q], w11 = W1[p] * W1[q];
#pragma unroll
            for (int mi = 0; mi < 4; mi++)
#pragma unroll
                for (int nj = 0; nj < 2; nj++) {
                    if (w00 != 0.f) yac[0][0][mi][nj] += w00 * mac[mi][nj];
                    if (w01 != 0.f) yac[0][1][mi][nj] += w01 * mac[mi][nj];
                    if (w10 != 0.f) yac[1][0][mi][nj] += w10 * mac[mi][nj];
                    if (w11 != 0.f) yac[1][1][mi][nj] += w11 * mac[mi][nj];
                }
        }
        __syncthreads();
    }

    // ---- writeout: D frag: col(bij)=lane&15, row(kout)=(lane>>4)*4+r ----
    const int lr = lane & 15, rg = lane >> 4;
#pragma unroll
    for (int mi = 0; mi < 4; mi++) {
#pragma unroll
        for (int r = 0; r < 4; r++) {
            const int kout = m0 + wm * 64 + mi * 16 + rg * 4 + r;
            const float bvv = bias[kout];
#pragma unroll
            for (int nj = 0; nj < 2; nj++) {
                const int bij = n0 + wn * 32 + nj * 16 + lr;
                const int bb = bij >> 10, ti = (bij >> 5) & 31, tj = bij & 31;
                float* op = out + (((size_t)bb * COUT + kout) * HH + 2 * ti) * WW + 2 * tj;
                *reinterpret_cast<float2*>(op) =
                    make_float2(yac[0][0][mi][nj][r] + bvv, yac[0][1][mi][nj][r] + bvv);
                *reinterpret_cast<float2*>(op + WW) =
                    make_float2(yac[1][0][mi][nj][r] + bvv, yac[1][1][mi][nj][r] + bvv);
            }
        }
    }
}

// ---------------------------------------------------------------------------
extern "C" void kernel_launch(void* const* d_in, const int* in_sizes, int n_in,
                              void* d_out, int out_size, void* d_ws, size_t ws_size,
                              hipStream_t stream) {
    const float* X    = (const float*)d_in[0];
    const float* w    = (const float*)d_in[1];
    const float* bias = (const float*)d_in[2];
    float* out        = (float*)d_out;

    __hip_bfloat16* U = (__hip_bfloat16*)d_ws;                       // 1 MB
    __hip_bfloat16* V = (__hip_bfloat16*)((char*)d_ws + (1u << 20)); // 64 MB

    wg_wtrans<<<(COUT * CIN + 255) / 256, 256, 0, stream>>>(w, U);
    wg_itrans<<<dim3(CIN / 32, TH, BATCH), 1024, 0, stream>>>(X, V);
    wg_gemm3<<<2 * (NT / 64), 256, 0, stream>>>(U, V, bias, out);
}

// Round 4
// 85.399 us; speedup vs baseline: 3.1964x; 1.0409x over previous
//
#include <hip/hip_runtime.h>
#include <hip/hip_bf16.h>
#include <cstdint>

#define CIN   128
#define COUT  256
#define BATCH 16
#define HH    64
#define WW    64
#define TH    32
#define TW    32
#define NT    (BATCH*TH*TW)   /* 16384 winograd tiles */
#define APQ   (COUT*CIN)      /* U plane: 32768 elems */
#define BPQ   (NT*CIN)        /* V plane: 2097152 elems */

typedef __bf16 bf16x8 __attribute__((ext_vector_type(8)));
typedef float  f32x4  __attribute__((ext_vector_type(4)));

__device__ __forceinline__ void gload16(const void* g, void* l) {
    __builtin_amdgcn_global_load_lds(
        (const __attribute__((address_space(1))) uint32_t*)g,
        (__attribute__((address_space(3))) uint32_t*)l, 16, 0, 0);
}

// ---------------------------------------------------------------------------
// Kernel 1: weight transform  U[pq][k][c] = (G w G^T)[p][q], bf16
// ---------------------------------------------------------------------------
__global__ __launch_bounds__(256) void wg_wtrans(const float* __restrict__ w,
                                                 __hip_bfloat16* __restrict__ U) {
    int idx = blockIdx.x * 256 + threadIdx.x;       // idx = k*CIN + c
    if (idx >= COUT * CIN) return;
    const float* wp = w + idx * 9;
    float g[3][3];
#pragma unroll
    for (int x = 0; x < 3; x++)
#pragma unroll
        for (int y = 0; y < 3; y++) g[x][y] = wp[x * 3 + y];

    float t[4][3];
#pragma unroll
    for (int y = 0; y < 3; y++) {
        t[0][y] = g[0][y];
        t[1][y] = 0.5f * (g[0][y] + g[1][y] + g[2][y]);
        t[2][y] = 0.5f * (g[0][y] - g[1][y] + g[2][y]);
        t[3][y] = g[2][y];
    }
#pragma unroll
    for (int p = 0; p < 4; p++) {
        float u0 = t[p][0];
        float u1 = 0.5f * (t[p][0] + t[p][1] + t[p][2]);
        float u2 = 0.5f * (t[p][0] - t[p][1] + t[p][2]);
        float u3 = t[p][2];
        U[(p * 4 + 0) * APQ + idx] = __float2bfloat16(u0);
        U[(p * 4 + 1) * APQ + idx] = __float2bfloat16(u1);
        U[(p * 4 + 2) * APQ + idx] = __float2bfloat16(u2);
        U[(p * 4 + 3) * APQ + idx] = __float2bfloat16(u3);
    }
}

// ---------------------------------------------------------------------------
// Kernel 2: input transform  V[pq][bij][c] = (BT d BT^T)[p][q], bf16
// ---------------------------------------------------------------------------
__global__ __launch_bounds__(1024) void wg_itrans(const float* __restrict__ X,
                                                  __hip_bfloat16* __restrict__ V) {
    __shared__ float lds[32 * 265];
    const int c0 = blockIdx.x * 32;
    const int i  = blockIdx.y;
    const int b  = blockIdx.z;
    const int tid = threadIdx.x;

    for (int t = tid; t < 32 * 4; t += 1024) {
        int cc = t >> 2, r = t & 3;
        lds[cc * 265 + r * 66 + 0]  = 0.f;
        lds[cc * 265 + r * 66 + 65] = 0.f;
    }
    for (int t = tid; t < 32 * 4 * 64; t += 1024) {
        int x = t & 63, r = (t >> 6) & 3, cc = t >> 8;
        int y = 2 * i - 1 + r;
        float v = 0.f;
        if (y >= 0 && y < HH) v = X[(((b * CIN) + (c0 + cc)) * HH + y) * WW + x];
        lds[cc * 265 + r * 66 + 1 + x] = v;
    }
    __syncthreads();

    const int c = tid & 31;
    const int j = tid >> 5;
    const float* base = &lds[c * 265 + 2 * j];

    float t0[4], t1[4], t2[4], t3[4];
#pragma unroll
    for (int y = 0; y < 4; y++) {
        float a  = base[0 * 66 + y];
        float bb = base[1 * 66 + y];
        float cc = base[2 * 66 + y];
        float dd = base[3 * 66 + y];
        t0[y] = a - cc;
        t1[y] = bb + cc;
        t2[y] = cc - bb;
        t3[y] = bb - dd;
    }
    float vm[4][4];
#pragma unroll
    for (int p = 0; p < 4; p++) {
        const float* tp = (p == 0) ? t0 : (p == 1) ? t1 : (p == 2) ? t2 : t3;
        vm[p][0] = tp[0] - tp[2];
        vm[p][1] = tp[1] + tp[2];
        vm[p][2] = tp[2] - tp[1];
        vm[p][3] = tp[1] - tp[3];
    }

    const int bij = b * (TH * TW) + i * TW + j;
    const int vo  = bij * CIN + (c0 + c);
#pragma unroll
    for (int p = 0; p < 4; p++)
#pragma unroll
        for (int q = 0; q < 4; q++)
            V[(size_t)(p * 4 + q) * BPQ + vo] = __float2bfloat16(vm[p][q]);
}

// ---------------------------------------------------------------------------
// Kernel 3: fused GEMM + output transform, counted-vmcnt pipeline (T3/T4).
// Block [128 kout x 64 bij], 4 waves (2m x 2n), wave tile 64x32 (4x2 frags).
// 4-buffer LDS rotation, stage depth 2, raw s_barrier + s_waitcnt vmcnt(6)
// (never 0 in steady state). Per-pq fold into 4 register Y-planes.
// ---------------------------------------------------------------------------
#define BUFSZ 12288

__global__ __launch_bounds__(256, 2) void wg_gemm4(const __hip_bfloat16* __restrict__ U,
                                                   const __hip_bfloat16* __restrict__ V,
                                                   const float* __restrict__ bias,
                                                   float* __restrict__ out) {
    __shared__ char lds[4 * BUFSZ];      // per buf: A 8192B (128x32), B 4096B (64x32)

    // bijective XCD swizzle (512 % 8 == 0): 64 consecutive wg per XCD
    int orig = blockIdx.x;
    int wg   = (orig & 7) * 64 + (orig >> 3);
    const int mt = wg & 1, nt = wg >> 1;
    const int m0 = mt * 128, n0 = nt * 64;

    const int tid  = threadIdx.x;
    const int lane = tid & 63;
    const int wave = tid >> 6;
    const int wm = wave >> 1, wn = wave & 1;

    // staging thread-constants: chunk c -> frag=c>>6, kb=(c>>4)&3, lr=c&15
    const int kcol  = ((tid >> 4) & 3) * 8;
    const int arow0 = (tid >> 6) * 16 + (tid & 15);
    const int brow  = ((tid >> 6) & 3) * 16 + (tid & 15);
    const __hip_bfloat16* pa0 = U + (m0 + arow0) * CIN + kcol;
    const __hip_bfloat16* pa1 = U + (m0 + 64 + arow0) * CIN + kcol;
    const __hip_bfloat16* pb  = V + (size_t)(n0 + brow) * CIN + kcol;

    const int ldsA0 = wave * 1024;
    const int ldsA1 = 4096 + wave * 1024;
    const int ldsB  = 8192 + wave * 1024;

    auto stage = [&](int t, int buf) {
        const int pq = t >> 2, kk = t & 3;
        char* base = lds + buf * BUFSZ;
        gload16(pa0 + pq * APQ + kk * 32, base + ldsA0);
        gload16(pa1 + pq * APQ + kk * 32, base + ldsA1);
        gload16(pb + (size_t)pq * BPQ + kk * 32, base + ldsB);
    };

    f32x4 yac[2][2][4][2];               // [x][y][mi][nj] = 128 VGPR
#pragma unroll
    for (int x = 0; x < 2; x++)
#pragma unroll
        for (int y = 0; y < 2; y++)
#pragma unroll
            for (int mi = 0; mi < 4; mi++)
#pragma unroll
                for (int nj = 0; nj < 2; nj++) yac[x][y][mi][nj] = (f32x4){0.f, 0.f, 0.f, 0.f};
    f32x4 mac[4][2];
    const f32x4 fz = (f32x4){0.f, 0.f, 0.f, 0.f};

    stage(0, 0);
    stage(1, 1);

#pragma unroll
    for (int t = 0; t < 64; ++t) {
        const int pq = t >> 2, kk = t & 3, cur = t & 3;
        if (t < 62) stage(t + 2, (t + 2) & 3);

        // counted drain: keep later stages in flight across the barrier
        if (t < 62)      asm volatile("s_waitcnt vmcnt(6)" ::: "memory");
        else if (t == 62) asm volatile("s_waitcnt vmcnt(3)" ::: "memory");
        else              asm volatile("s_waitcnt vmcnt(0)" ::: "memory");
        __builtin_amdgcn_s_barrier();
        __builtin_amdgcn_sched_barrier(0);

        const char* base = lds + cur * BUFSZ;
        bf16x8 av[4], bv[2];
#pragma unroll
        for (int mi = 0; mi < 4; mi++)
            av[mi] = *reinterpret_cast<const bf16x8*>(base + ((wm * 4 + mi) * 64 + lane) * 16);
#pragma unroll
        for (int nj = 0; nj < 2; nj++)
            bv[nj] = *reinterpret_cast<const bf16x8*>(base + 8192 + ((wn * 2 + nj) * 64 + lane) * 16);

#pragma unroll
        for (int mi = 0; mi < 4; mi++)
#pragma unroll
            for (int nj = 0; nj < 2; nj++)
                mac[mi][nj] = __builtin_amdgcn_mfma_f32_16x16x32_bf16(
                    av[mi], bv[nj], (kk == 0) ? fz : mac[mi][nj], 0, 0, 0);

        if (kk == 3) {                   // fold M[pq] into Y with AT weights
            const int p = pq >> 2, q = pq & 3;
            constexpr float W0[4] = {1.f, 1.f, 1.f, 0.f};
            constexpr float W1[4] = {0.f, 1.f, -1.f, -1.f};
            const float w00 = W0[p] * W0[q], w01 = W0[p] * W1[q];
            const float w10 = W1[p] * W0[q], w11 = W1[p] * W1[q];
#pragma unroll
            for (int mi = 0; mi < 4; mi++)
#pragma unroll
                for (int nj = 0; nj < 2; nj++) {
                    if (w00 != 0.f) yac[0][0][mi][nj] += w00 * mac[mi][nj];
                    if (w01 != 0.f) yac[0][1][mi][nj] += w01 * mac[mi][nj];
                    if (w10 != 0.f) yac[1][0][mi][nj] += w10 * mac[mi][nj];
                    if (w11 != 0.f) yac[1][1][mi][nj] += w11 * mac[mi][nj];
                }
        }
    }

    // ---- writeout: D frag: col(bij)=lane&15, row(kout)=(lane>>4)*4+r ----
    const int lr = lane & 15, rg = lane >> 4;
#pragma unroll
    for (int mi = 0; mi < 4; mi++) {
#pragma unroll
        for (int r = 0; r < 4; r++) {
            const int kout = m0 + wm * 64 + mi * 16 + rg * 4 + r;
            const float bvv = bias[kout];
#pragma unroll
            for (int nj = 0; nj < 2; nj++) {
                const int bij = n0 + wn * 32 + nj * 16 + lr;
                const int bb = bij >> 10, ti = (bij >> 5) & 31, tj = bij & 31;
                float* op = out + (((size_t)bb * COUT + kout) * HH + 2 * ti) * WW + 2 * tj;
                *reinterpret_cast<float2*>(op) =
                    make_float2(yac[0][0][mi][nj][r] + bvv, yac[0][1][mi][nj][r] + bvv);
                *reinterpret_cast<float2*>(op + WW) =
                    make_float2(yac[1][0][mi][nj][r] + bvv, yac[1][1][mi][nj][r] + bvv);
            }
        }
    }
}

// ---------------------------------------------------------------------------
extern "C" void kernel_launch(void* const* d_in, const int* in_sizes, int n_in,
                              void* d_out, int out_size, void* d_ws, size_t ws_size,
                              hipStream_t stream) {
    const float* X    = (const float*)d_in[0];
    const float* w    = (const float*)d_in[1];
    const float* bias = (const float*)d_in[2];
    float* out        = (float*)d_out;

    __hip_bfloat16* U = (__hip_bfloat16*)d_ws;                       // 1 MB
    __hip_bfloat16* V = (__hip_bfloat16*)((char*)d_ws + (1u << 20)); // 64 MB

    wg_wtrans<<<(COUT * CIN + 255) / 256, 256, 0, stream>>>(w, U);
    wg_itrans<<<dim3(CIN / 32, TH, BATCH), 1024, 0, stream>>>(X, V);
    wg_gemm4<<<2 * (NT / 64), 256, 0, stream>>>(U, V, bias, out);
}

// Round 5
// 78.014 us; speedup vs baseline: 3.4990x; 1.0947x over previous
//
#include <hip/hip_runtime.h>
#include <hip/hip_bf16.h>
#include <cstdint>

#define CIN   128
#define COUT  256
#define BATCH 16
#define HH    64
#define WW    64
#define TH    32
#define TW    32
#define NT    (BATCH*TH*TW)   /* 16384 winograd tiles */
#define APQ   (COUT*CIN)      /* U plane: 32768 elems */
#define BPQ   (NT*CIN)        /* V plane: 2097152 elems */

typedef __bf16 bf16x8 __attribute__((ext_vector_type(8)));
typedef float  f32x4  __attribute__((ext_vector_type(4)));

__device__ __forceinline__ void gload16(const void* g, void* l) {
    __builtin_amdgcn_global_load_lds(
        (const __attribute__((address_space(1))) uint32_t*)g,
        (__attribute__((address_space(3))) uint32_t*)l, 16, 0, 0);
}

// ---------------------------------------------------------------------------
// Kernel 1: weight transform  U[pq][k][c] = (G w G^T)[p][q], bf16
// ---------------------------------------------------------------------------
__global__ __launch_bounds__(256) void wg_wtrans(const float* __restrict__ w,
                                                 __hip_bfloat16* __restrict__ U) {
    int idx = blockIdx.x * 256 + threadIdx.x;       // idx = k*CIN + c
    if (idx >= COUT * CIN) return;
    const float* wp = w + idx * 9;
    float g[3][3];
#pragma unroll
    for (int x = 0; x < 3; x++)
#pragma unroll
        for (int y = 0; y < 3; y++) g[x][y] = wp[x * 3 + y];

    float t[4][3];
#pragma unroll
    for (int y = 0; y < 3; y++) {
        t[0][y] = g[0][y];
        t[1][y] = 0.5f * (g[0][y] + g[1][y] + g[2][y]);
        t[2][y] = 0.5f * (g[0][y] - g[1][y] + g[2][y]);
        t[3][y] = g[2][y];
    }
#pragma unroll
    for (int p = 0; p < 4; p++) {
        float u0 = t[p][0];
        float u1 = 0.5f * (t[p][0] + t[p][1] + t[p][2]);
        float u2 = 0.5f * (t[p][0] - t[p][1] + t[p][2]);
        float u3 = t[p][2];
        U[(p * 4 + 0) * APQ + idx] = __float2bfloat16(u0);
        U[(p * 4 + 1) * APQ + idx] = __float2bfloat16(u1);
        U[(p * 4 + 2) * APQ + idx] = __float2bfloat16(u2);
        U[(p * 4 + 3) * APQ + idx] = __float2bfloat16(u3);
    }
}

// ---------------------------------------------------------------------------
// Kernel 2: input transform  V[pq][bij][c] = (BT d BT^T)[p][q], bf16
// ---------------------------------------------------------------------------
__global__ __launch_bounds__(1024) void wg_itrans(const float* __restrict__ X,
                                                  __hip_bfloat16* __restrict__ V) {
    __shared__ float lds[32 * 265];
    const int c0 = blockIdx.x * 32;
    const int i  = blockIdx.y;
    const int b  = blockIdx.z;
    const int tid = threadIdx.x;

    for (int t = tid; t < 32 * 4; t += 1024) {
        int cc = t >> 2, r = t & 3;
        lds[cc * 265 + r * 66 + 0]  = 0.f;
        lds[cc * 265 + r * 66 + 65] = 0.f;
    }
    for (int t = tid; t < 32 * 4 * 64; t += 1024) {
        int x = t & 63, r = (t >> 6) & 3, cc = t >> 8;
        int y = 2 * i - 1 + r;
        float v = 0.f;
        if (y >= 0 && y < HH) v = X[(((b * CIN) + (c0 + cc)) * HH + y) * WW + x];
        lds[cc * 265 + r * 66 + 1 + x] = v;
    }
    __syncthreads();

    const int c = tid & 31;
    const int j = tid >> 5;
    const float* base = &lds[c * 265 + 2 * j];

    float t0[4], t1[4], t2[4], t3[4];
#pragma unroll
    for (int y = 0; y < 4; y++) {
        float a  = base[0 * 66 + y];
        float bb = base[1 * 66 + y];
        float cc = base[2 * 66 + y];
        float dd = base[3 * 66 + y];
        t0[y] = a - cc;
        t1[y] = bb + cc;
        t2[y] = cc - bb;
        t3[y] = bb - dd;
    }
    float vm[4][4];
#pragma unroll
    for (int p = 0; p < 4; p++) {
        const float* tp = (p == 0) ? t0 : (p == 1) ? t1 : (p == 2) ? t2 : t3;
        vm[p][0] = tp[0] - tp[2];
        vm[p][1] = tp[1] + tp[2];
        vm[p][2] = tp[2] - tp[1];
        vm[p][3] = tp[1] - tp[3];
    }

    const int bij = b * (TH * TW) + i * TW + j;
    const int vo  = bij * CIN + (c0 + c);
#pragma unroll
    for (int p = 0; p < 4; p++)
#pragma unroll
        for (int q = 0; q < 4; q++)
            V[(size_t)(p * 4 + q) * BPQ + vo] = __float2bfloat16(vm[p][q]);
}

// ---------------------------------------------------------------------------
// Kernel 3: fused GEMM + output transform.
// Block [128 kout x 128 bij], 512 thr = 8 waves (2m x 4n), wave tile 64x32.
// K_eff = 16 pq * 128 cin = 2048, BK=64 -> 32 iterations.
// 4 LDS buffers (A 16KB + B 16KB each = 128 KB total), prefetch depth 3,
// counted vmcnt(8) steady state; stage issued AFTER the barrier (race-free).
// Fragment-major LDS (lane-linear ds_read_b128, zero bank conflicts).
// Per-pq fold into 4 register Y-planes with compile-time AT weights.
// ---------------------------------------------------------------------------
#define ABYTES 16384
#define BUFSZ  32768

__global__ __launch_bounds__(512, 2) void wg_gemm5(const __hip_bfloat16* __restrict__ U,
                                                   const __hip_bfloat16* __restrict__ V,
                                                   const float* __restrict__ bias,
                                                   float* __restrict__ out) {
    __shared__ char lds[4 * BUFSZ];      // 128 KB

    // bijective XCD swizzle (256 % 8 == 0): 32 consecutive wg per XCD
    int orig = blockIdx.x;
    int wg   = (orig & 7) * 32 + (orig >> 3);
    const int mt = wg & 1, nt = wg >> 1;
    const int m0 = mt * 128, n0 = nt * 128;

    const int tid  = threadIdx.x;
    const int lane = tid & 63;
    const int wave = tid >> 6;
    const int wm = wave >> 2, wn = wave & 3;

    // staging: chunk c (0..1023) -> fr=c>>7, kk=(c>>6)&1, lane-in-frag=c&63
    // global row = fr*16 + (c&15), kcol = kk*32 + ((c>>4)&3)*8
    const __hip_bfloat16* pa[2];
    const __hip_bfloat16* pb[2];
    int ldsoffA[2], ldsoffB[2];
#pragma unroll
    for (int ch = 0; ch < 2; ch++) {
        int c = ch * 512 + tid;
        int row  = (c >> 7) * 16 + (c & 15);
        int kcol = ((c >> 6) & 1) * 32 + ((c >> 4) & 3) * 8;
        pa[ch] = U + (m0 + row) * CIN + kcol;
        pb[ch] = V + (size_t)(n0 + row) * CIN + kcol;
        ldsoffA[ch] = c * 16;
        ldsoffB[ch] = ABYTES + c * 16;
    }

    auto stage = [&](int t, int buf) {
        const int pq    = t >> 1;
        const int kbase = (t & 1) * 64;
        char* base = lds + buf * BUFSZ;
#pragma unroll
        for (int ch = 0; ch < 2; ch++)
            gload16(pa[ch] + pq * APQ + kbase, base + ldsoffA[ch]);
#pragma unroll
        for (int ch = 0; ch < 2; ch++)
            gload16(pb[ch] + (size_t)pq * BPQ + kbase, base + ldsoffB[ch]);
    };

    f32x4 yac[2][2][4][2];               // [x][y][mi][nj] = 128 VGPR
#pragma unroll
    for (int x = 0; x < 2; x++)
#pragma unroll
        for (int y = 0; y < 2; y++)
#pragma unroll
            for (int mi = 0; mi < 4; mi++)
#pragma unroll
                for (int nj = 0; nj < 2; nj++) yac[x][y][mi][nj] = (f32x4){0.f, 0.f, 0.f, 0.f};
    f32x4 mac[4][2];
    const f32x4 fz = (f32x4){0.f, 0.f, 0.f, 0.f};

    stage(0, 0);
    stage(1, 1);
    stage(2, 2);

#pragma unroll
    for (int t = 0; t < 32; ++t) {
        const int cur = t & 3;

        // counted drain: keep the 2 younger stages (8 loads) in flight
        if (t <= 29)      asm volatile("s_waitcnt vmcnt(8)" ::: "memory");
        else if (t == 30) asm volatile("s_waitcnt vmcnt(4)" ::: "memory");
        else              asm volatile("s_waitcnt vmcnt(0)" ::: "memory");
        __builtin_amdgcn_s_barrier();
        __builtin_amdgcn_sched_barrier(0);

        if (t <= 28) stage(t + 3, (t + 3) & 3);   // post-barrier: race-free

        const char* base = lds + cur * BUFSZ;
        bf16x8 av[4][2], bv[2][2];
#pragma unroll
        for (int mi = 0; mi < 4; mi++)
#pragma unroll
            for (int kk = 0; kk < 2; kk++)
                av[mi][kk] = *reinterpret_cast<const bf16x8*>(
                    base + (((wm * 4 + mi) * 2 + kk) * 64 + lane) * 16);
#pragma unroll
        for (int nj = 0; nj < 2; nj++)
#pragma unroll
            for (int kk = 0; kk < 2; kk++)
                bv[nj][kk] = *reinterpret_cast<const bf16x8*>(
                    base + ABYTES + (((wn * 2 + nj) * 2 + kk) * 64 + lane) * 16);

        __builtin_amdgcn_s_setprio(1);
#pragma unroll
        for (int kk = 0; kk < 2; kk++)
#pragma unroll
            for (int mi = 0; mi < 4; mi++)
#pragma unroll
                for (int nj = 0; nj < 2; nj++)
                    mac[mi][nj] = __builtin_amdgcn_mfma_f32_16x16x32_bf16(
                        av[mi][kk], bv[nj][kk],
                        ((t & 1) == 0 && kk == 0) ? fz : mac[mi][nj], 0, 0, 0);
        __builtin_amdgcn_s_setprio(0);

        if (t & 1) {                     // pq = t>>1 complete: fold into Y
            const int pq = t >> 1;
            const int p = pq >> 2, q = pq & 3;
            constexpr float W0[4] = {1.f, 1.f, 1.f, 0.f};
            constexpr float W1[4] = {0.f, 1.f, -1.f, -1.f};
            const float w00 = W0[p] * W0[q], w01 = W0[p] * W1[q];
            const float w10 = W1[p] * W0[q], w11 = W1[p] * W1[q];
#pragma unroll
            for (int mi = 0; mi < 4; mi++)
#pragma unroll
                for (int nj = 0; nj < 2; nj++) {
                    if (w00 != 0.f) yac[0][0][mi][nj] += w00 * mac[mi][nj];
                    if (w01 != 0.f) yac[0][1][mi][nj] += w01 * mac[mi][nj];
                    if (w10 != 0.f) yac[1][0][mi][nj] += w10 * mac[mi][nj];
                    if (w11 != 0.f) yac[1][1][mi][nj] += w11 * mac[mi][nj];
                }
        }
    }

    // ---- writeout: D frag: col(bij)=lane&15, row(kout)=(lane>>4)*4+r ----
    const int lr = lane & 15, rg = lane >> 4;
#pragma unroll
    for (int mi = 0; mi < 4; mi++) {
#pragma unroll
        for (int r = 0; r < 4; r++) {
            const int kout = m0 + wm * 64 + mi * 16 + rg * 4 + r;
            const float bvv = bias[kout];
#pragma unroll
            for (int nj = 0; nj < 2; nj++) {
                const int bij = n0 + wn * 32 + nj * 16 + lr;
                const int bb = bij >> 10, ti = (bij >> 5) & 31, tj = bij & 31;
                float* op = out + (((size_t)bb * COUT + kout) * HH + 2 * ti) * WW + 2 * tj;
                *reinterpret_cast<float2*>(op) =
                    make_float2(yac[0][0][mi][nj][r] + bvv, yac[0][1][mi][nj][r] + bvv);
                *reinterpret_cast<float2*>(op + WW) =
                    make_float2(yac[1][0][mi][nj][r] + bvv, yac[1][1][mi][nj][r] + bvv);
            }
        }
    }
}

// ---------------------------------------------------------------------------
extern "C" void kernel_launch(void* const* d_in, const int* in_sizes, int n_in,
                              void* d_out, int out_size, void* d_ws, size_t ws_size,
                              hipStream_t stream) {
    const float* X    = (const float*)d_in[0];
    const float* w    = (const float*)d_in[1];
    const float* bias = (const float*)d_in[2];
    float* out        = (float*)d_out;

    __hip_bfloat16* U = (__hip_bfloat16*)d_ws;                       // 1 MB
    __hip_bfloat16* V = (__hip_bfloat16*)((char*)d_ws + (1u << 20)); // 64 MB

    wg_wtrans<<<(COUT * CIN + 255) / 256, 256, 0, stream>>>(w, U);
    wg_itrans<<<dim3(CIN / 32, TH, BATCH), 1024, 0, stream>>>(X, V);
    wg_gemm5<<<(COUT / 128) * (NT / 128), 512, 0, stream>>>(U, V, bias, out);
}

// Round 6
// 71.585 us; speedup vs baseline: 3.8132x; 1.0898x over previous
//
#include <hip/hip_runtime.h>
#include <hip/hip_bf16.h>
#include <cstdint>

#define CIN   128
#define COUT  256
#define BATCH 16
#define HH    64
#define WW    64
#define TH    32
#define TW    32
#define NT    (BATCH*TH*TW)   /* 16384 winograd tiles */
#define APQ   (COUT*CIN)      /* U plane: 32768 elems */
#define BPQ   (NT*CIN)        /* V plane: 2097152 elems */

typedef __bf16 bf16x8 __attribute__((ext_vector_type(8)));
typedef float  f32x4  __attribute__((ext_vector_type(4)));

__device__ __forceinline__ void gload16(const void* g, void* l) {
    __builtin_amdgcn_global_load_lds(
        (const __attribute__((address_space(1))) uint32_t*)g,
        (__attribute__((address_space(3))) uint32_t*)l, 16, 0, 0);
}

// ---------------------------------------------------------------------------
// Kernel 1: weight transform  U[pq][k][c] = (G w G^T)[p][q], bf16
// ---------------------------------------------------------------------------
__global__ __launch_bounds__(256) void wg_wtrans(const float* __restrict__ w,
                                                 __hip_bfloat16* __restrict__ U) {
    int idx = blockIdx.x * 256 + threadIdx.x;       // idx = k*CIN + c
    if (idx >= COUT * CIN) return;
    const float* wp = w + idx * 9;
    float g[3][3];
#pragma unroll
    for (int x = 0; x < 3; x++)
#pragma unroll
        for (int y = 0; y < 3; y++) g[x][y] = wp[x * 3 + y];

    float t[4][3];
#pragma unroll
    for (int y = 0; y < 3; y++) {
        t[0][y] = g[0][y];
        t[1][y] = 0.5f * (g[0][y] + g[1][y] + g[2][y]);
        t[2][y] = 0.5f * (g[0][y] - g[1][y] + g[2][y]);
        t[3][y] = g[2][y];
    }
#pragma unroll
    for (int p = 0; p < 4; p++) {
        float u0 = t[p][0];
        float u1 = 0.5f * (t[p][0] + t[p][1] + t[p][2]);
        float u2 = 0.5f * (t[p][0] - t[p][1] + t[p][2]);
        float u3 = t[p][2];
        U[(p * 4 + 0) * APQ + idx] = __float2bfloat16(u0);
        U[(p * 4 + 1) * APQ + idx] = __float2bfloat16(u1);
        U[(p * 4 + 2) * APQ + idx] = __float2bfloat16(u2);
        U[(p * 4 + 3) * APQ + idx] = __float2bfloat16(u3);
    }
}

// ---------------------------------------------------------------------------
// Kernel 2: input transform  V[pq][bij][c] = (BT d BT^T)[p][q], bf16
// ---------------------------------------------------------------------------
__global__ __launch_bounds__(1024) void wg_itrans(const float* __restrict__ X,
                                                  __hip_bfloat16* __restrict__ V) {
    __shared__ float lds[32 * 265];
    const int c0 = blockIdx.x * 32;
    const int i  = blockIdx.y;
    const int b  = blockIdx.z;
    const int tid = threadIdx.x;

    for (int t = tid; t < 32 * 4; t += 1024) {
        int cc = t >> 2, r = t & 3;
        lds[cc * 265 + r * 66 + 0]  = 0.f;
        lds[cc * 265 + r * 66 + 65] = 0.f;
    }
    for (int t = tid; t < 32 * 4 * 64; t += 1024) {
        int x = t & 63, r = (t >> 6) & 3, cc = t >> 8;
        int y = 2 * i - 1 + r;
        float v = 0.f;
        if (y >= 0 && y < HH) v = X[(((b * CIN) + (c0 + cc)) * HH + y) * WW + x];
        lds[cc * 265 + r * 66 + 1 + x] = v;
    }
    __syncthreads();

    const int c = tid & 31;
    const int j = tid >> 5;
    const float* base = &lds[c * 265 + 2 * j];

    float t0[4], t1[4], t2[4], t3[4];
#pragma unroll
    for (int y = 0; y < 4; y++) {
        float a  = base[0 * 66 + y];
        float bb = base[1 * 66 + y];
        float cc = base[2 * 66 + y];
        float dd = base[3 * 66 + y];
        t0[y] = a - cc;
        t1[y] = bb + cc;
        t2[y] = cc - bb;
        t3[y] = bb - dd;
    }
    float vm[4][4];
#pragma unroll
    for (int p = 0; p < 4; p++) {
        const float* tp = (p == 0) ? t0 : (p == 1) ? t1 : (p == 2) ? t2 : t3;
        vm[p][0] = tp[0] - tp[2];
        vm[p][1] = tp[1] + tp[2];
        vm[p][2] = tp[2] - tp[1];
        vm[p][3] = tp[1] - tp[3];
    }

    const int bij = b * (TH * TW) + i * TW + j;
    const int vo  = bij * CIN + (c0 + c);
#pragma unroll
    for (int p = 0; p < 4; p++)
#pragma unroll
        for (int q = 0; q < 4; q++)
            V[(size_t)(p * 4 + q) * BPQ + vo] = __float2bfloat16(vm[p][q]);
}

// ---------------------------------------------------------------------------
// Kernel 3: fused GEMM + output transform.
// Block [128 kout x 128 bij], 512 thr = 8 waves (2m x 4n), wave tile 64x32.
// BK=64, 32 iterations. 4 LDS buffers, prefetch depth 3, counted vmcnt(8).
// CONTIGUOUS staging: each LDS buffer is the linear byte image of the tile's
// rows (128 B each) with an XOR granule swizzle applied on the SOURCE side
// (rule 21: permutation stays inside each wave's 1024 B window -> coalescing
// preserved at 16 lines/wave-instr). ds_read applies the same XOR ->
// conflict-free b128 reads (each 8-lane phase hits all 32 banks).
// Per-pq fold into 4 register Y-planes with compile-time AT weights.
// ---------------------------------------------------------------------------
#define ABYTES 16384
#define BUFSZ  32768

__global__ __launch_bounds__(512, 2) void wg_gemm6(const __hip_bfloat16* __restrict__ U,
                                                   const __hip_bfloat16* __restrict__ V,
                                                   const float* __restrict__ bias,
                                                   float* __restrict__ out) {
    __shared__ char lds[4 * BUFSZ];      // 128 KB

    // bijective XCD swizzle (256 % 8 == 0): 32 consecutive wg per XCD
    int orig = blockIdx.x;
    int wg   = (orig & 7) * 32 + (orig >> 3);
    const int mt = wg & 1, nt = wg >> 1;
    const int m0 = mt * 128, n0 = nt * 128;

    const int tid  = threadIdx.x;
    const int lane = tid & 63;
    const int wave = tid >> 6;
    const int wm = wave >> 2, wn = wave & 3;

    // staging: chunk c holds tile granule (row R=c>>3, gran G=(c&7)^(R&7));
    // source = row-major U/V row (m0|n0)+R, 16B granule G of the 128B k-slice
    const __hip_bfloat16* pa[2];
    const __hip_bfloat16* pb[2];
    int ldsA[2], ldsB[2];
#pragma unroll
    for (int ch = 0; ch < 2; ch++) {
        int c = ch * 512 + tid;
        int R = c >> 3;
        int G = (c & 7) ^ (R & 7);
        pa[ch] = U + (m0 + R) * CIN + G * 8;
        pb[ch] = V + (size_t)(n0 + R) * CIN + G * 8;
        ldsA[ch] = c * 16;
        ldsB[ch] = ABYTES + c * 16;
    }

    auto stage = [&](int t, int buf) {
        const int pq = t >> 1;
        const int kb = (t & 1) * 64;
        char* base = lds + buf * BUFSZ;
        gload16(pa[0] + pq * APQ + kb, base + ldsA[0]);
        gload16(pa[1] + pq * APQ + kb, base + ldsA[1]);
        gload16(pb[0] + (size_t)pq * BPQ + kb, base + ldsB[0]);
        gload16(pb[1] + (size_t)pq * BPQ + kb, base + ldsB[1]);
    };

    // ds_read offsets: row r, k-granule g -> byte r*128 + ((g ^ (r&7))<<4)
    const int la = lane & 15, hq = lane >> 4, l7 = lane & 7;
    int aoff[2], boff[2];
#pragma unroll
    for (int kk = 0; kk < 2; kk++) {
        int g = (kk * 4 + hq) ^ l7;
        aoff[kk] = (wm * 64 + la) * 128 + (g << 4);
        boff[kk] = ABYTES + (wn * 32 + la) * 128 + (g << 4);
    }

    f32x4 yac[2][2][4][2];               // [x][y][mi][nj] = 128 regs
#pragma unroll
    for (int x = 0; x < 2; x++)
#pragma unroll
        for (int y = 0; y < 2; y++)
#pragma unroll
            for (int mi = 0; mi < 4; mi++)
#pragma unroll
                for (int nj = 0; nj < 2; nj++) yac[x][y][mi][nj] = (f32x4){0.f, 0.f, 0.f, 0.f};
    f32x4 mac[4][2];
    const f32x4 fz = (f32x4){0.f, 0.f, 0.f, 0.f};

    stage(0, 0);
    stage(1, 1);
    stage(2, 2);

#pragma unroll
    for (int t = 0; t < 32; ++t) {
        const int cur = t & 3;

        // counted drain: keep the 2 younger stages (8 loads) in flight
        if (t <= 29)      asm volatile("s_waitcnt vmcnt(8)" ::: "memory");
        else if (t == 30) asm volatile("s_waitcnt vmcnt(4)" ::: "memory");
        else              asm volatile("s_waitcnt vmcnt(0)" ::: "memory");
        __builtin_amdgcn_s_barrier();
        __builtin_amdgcn_sched_barrier(0);

        if (t <= 28) stage(t + 3, (t + 3) & 3);   // post-barrier: race-free

        const char* base = lds + cur * BUFSZ;
        bf16x8 av[4][2], bv[2][2];
#pragma unroll
        for (int mi = 0; mi < 4; mi++)
#pragma unroll
            for (int kk = 0; kk < 2; kk++)
                av[mi][kk] = *reinterpret_cast<const bf16x8*>(base + aoff[kk] + mi * 2048);
#pragma unroll
        for (int nj = 0; nj < 2; nj++)
#pragma unroll
            for (int kk = 0; kk < 2; kk++)
                bv[nj][kk] = *reinterpret_cast<const bf16x8*>(base + boff[kk] + nj * 2048);

        __builtin_amdgcn_s_setprio(1);
#pragma unroll
        for (int kk = 0; kk < 2; kk++)
#pragma unroll
            for (int mi = 0; mi < 4; mi++)
#pragma unroll
                for (int nj = 0; nj < 2; nj++)
                    mac[mi][nj] = __builtin_amdgcn_mfma_f32_16x16x32_bf16(
                        av[mi][kk], bv[nj][kk],
                        ((t & 1) == 0 && kk == 0) ? fz : mac[mi][nj], 0, 0, 0);
        __builtin_amdgcn_s_setprio(0);

        if (t & 1) {                     // pq = t>>1 complete: fold into Y
            const int pq = t >> 1;
            const int p = pq >> 2, q = pq & 3;
            constexpr float W0[4] = {1.f, 1.f, 1.f, 0.f};
            constexpr float W1[4] = {0.f, 1.f, -1.f, -1.f};
            const float w00 = W0[p] * W0[q], w01 = W0[p] * W1[q];
            const float w10 = W1[p] * W0[q], w11 = W1[p] * W1[q];
#pragma unroll
            for (int mi = 0; mi < 4; mi++)
#pragma unroll
                for (int nj = 0; nj < 2; nj++) {
                    if (w00 != 0.f) yac[0][0][mi][nj] += w00 * mac[mi][nj];
                    if (w01 != 0.f) yac[0][1][mi][nj] += w01 * mac[mi][nj];
                    if (w10 != 0.f) yac[1][0][mi][nj] += w10 * mac[mi][nj];
                    if (w11 != 0.f) yac[1][1][mi][nj] += w11 * mac[mi][nj];
                }
        }
    }

    // ---- writeout: D frag: col(bij)=lane&15, row(kout)=(lane>>4)*4+r ----
    const int lr = lane & 15, rg = lane >> 4;
#pragma unroll
    for (int mi = 0; mi < 4; mi++) {
#pragma unroll
        for (int r = 0; r < 4; r++) {
            const int kout = m0 + wm * 64 + mi * 16 + rg * 4 + r;
            const float bvv = bias[kout];
#pragma unroll
            for (int nj = 0; nj < 2; nj++) {
                const int bij = n0 + wn * 32 + nj * 16 + lr;
                const int bb = bij >> 10, ti = (bij >> 5) & 31, tj = bij & 31;
                float* op = out + (((size_t)bb * COUT + kout) * HH + 2 * ti) * WW + 2 * tj;
                *reinterpret_cast<float2*>(op) =
                    make_float2(yac[0][0][mi][nj][r] + bvv, yac[0][1][mi][nj][r] + bvv);
                *reinterpret_cast<float2*>(op + WW) =
                    make_float2(yac[1][0][mi][nj][r] + bvv, yac[1][1][mi][nj][r] + bvv);
            }
        }
    }
}

// ---------------------------------------------------------------------------
extern "C" void kernel_launch(void* const* d_in, const int* in_sizes, int n_in,
                              void* d_out, int out_size, void* d_ws, size_t ws_size,
                              hipStream_t stream) {
    const float* X    = (const float*)d_in[0];
    const float* w    = (const float*)d_in[1];
    const float* bias = (const float*)d_in[2];
    float* out        = (float*)d_out;

    __hip_bfloat16* U = (__hip_bfloat16*)d_ws;                       // 1 MB
    __hip_bfloat16* V = (__hip_bfloat16*)((char*)d_ws + (1u << 20)); // 64 MB

    wg_wtrans<<<(COUT * CIN + 255) / 256, 256, 0, stream>>>(w, U);
    wg_itrans<<<dim3(CIN / 32, TH, BATCH), 1024, 0, stream>>>(X, V);
    wg_gemm6<<<(COUT / 128) * (NT / 128), 512, 0, stream>>>(U, V, bias, out);
}

// Round 7
// 70.007 us; speedup vs baseline: 3.8992x; 1.0225x over previous
//
#include <hip/hip_runtime.h>
#include <hip/hip_bf16.h>
#include <cstdint>

#define CIN   128
#define COUT  256
#define BATCH 16
#define HH    64
#define WW    64
#define TH    32
#define TW    32
#define NT    (BATCH*TH*TW)   /* 16384 winograd tiles */
#define APQ   (COUT*CIN)      /* U plane: 32768 elems */
#define BPQ   (NT*CIN)        /* V plane: 2097152 elems */

typedef __bf16 bf16x8 __attribute__((ext_vector_type(8)));
typedef float  f32x4  __attribute__((ext_vector_type(4)));

__device__ __forceinline__ void gload16(const void* g, void* l) {
    __builtin_amdgcn_global_load_lds(
        (const __attribute__((address_space(1))) uint32_t*)g,
        (__attribute__((address_space(3))) uint32_t*)l, 16, 0, 0);
}

// ---------------------------------------------------------------------------
// Kernel 1: weight transform  U[pq][k][c] = (G w G^T)[p][q], bf16
// ---------------------------------------------------------------------------
__global__ __launch_bounds__(256) void wg_wtrans(const float* __restrict__ w,
                                                 __hip_bfloat16* __restrict__ U) {
    int idx = blockIdx.x * 256 + threadIdx.x;       // idx = k*CIN + c
    if (idx >= COUT * CIN) return;
    const float* wp = w + idx * 9;
    float g[3][3];
#pragma unroll
    for (int x = 0; x < 3; x++)
#pragma unroll
        for (int y = 0; y < 3; y++) g[x][y] = wp[x * 3 + y];

    float t[4][3];
#pragma unroll
    for (int y = 0; y < 3; y++) {
        t[0][y] = g[0][y];
        t[1][y] = 0.5f * (g[0][y] + g[1][y] + g[2][y]);
        t[2][y] = 0.5f * (g[0][y] - g[1][y] + g[2][y]);
        t[3][y] = g[2][y];
    }
#pragma unroll
    for (int p = 0; p < 4; p++) {
        float u0 = t[p][0];
        float u1 = 0.5f * (t[p][0] + t[p][1] + t[p][2]);
        float u2 = 0.5f * (t[p][0] - t[p][1] + t[p][2]);
        float u3 = t[p][2];
        U[(p * 4 + 0) * APQ + idx] = __float2bfloat16(u0);
        U[(p * 4 + 1) * APQ + idx] = __float2bfloat16(u1);
        U[(p * 4 + 2) * APQ + idx] = __float2bfloat16(u2);
        U[(p * 4 + 3) * APQ + idx] = __float2bfloat16(u3);
    }
}

// ---------------------------------------------------------------------------
// Kernel 2: input transform  V[pq][bij][c] = (BT d BT^T)[p][q], bf16
// ---------------------------------------------------------------------------
__global__ __launch_bounds__(1024) void wg_itrans(const float* __restrict__ X,
                                                  __hip_bfloat16* __restrict__ V) {
    __shared__ float lds[32 * 265];
    const int c0 = blockIdx.x * 32;
    const int i  = blockIdx.y;
    const int b  = blockIdx.z;
    const int tid = threadIdx.x;

    for (int t = tid; t < 32 * 4; t += 1024) {
        int cc = t >> 2, r = t & 3;
        lds[cc * 265 + r * 66 + 0]  = 0.f;
        lds[cc * 265 + r * 66 + 65] = 0.f;
    }
    for (int t = tid; t < 32 * 4 * 64; t += 1024) {
        int x = t & 63, r = (t >> 6) & 3, cc = t >> 8;
        int y = 2 * i - 1 + r;
        float v = 0.f;
        if (y >= 0 && y < HH) v = X[(((b * CIN) + (c0 + cc)) * HH + y) * WW + x];
        lds[cc * 265 + r * 66 + 1 + x] = v;
    }
    __syncthreads();

    const int c = tid & 31;
    const int j = tid >> 5;
    const float* base = &lds[c * 265 + 2 * j];

    float t0[4], t1[4], t2[4], t3[4];
#pragma unroll
    for (int y = 0; y < 4; y++) {
        float a  = base[0 * 66 + y];
        float bb = base[1 * 66 + y];
        float cc = base[2 * 66 + y];
        float dd = base[3 * 66 + y];
        t0[y] = a - cc;
        t1[y] = bb + cc;
        t2[y] = cc - bb;
        t3[y] = bb - dd;
    }
    float vm[4][4];
#pragma unroll
    for (int p = 0; p < 4; p++) {
        const float* tp = (p == 0) ? t0 : (p == 1) ? t1 : (p == 2) ? t2 : t3;
        vm[p][0] = tp[0] - tp[2];
        vm[p][1] = tp[1] + tp[2];
        vm[p][2] = tp[2] - tp[1];
        vm[p][3] = tp[1] - tp[3];
    }

    const int bij = b * (TH * TW) + i * TW + j;
    const int vo  = bij * CIN + (c0 + c);
#pragma unroll
    for (int p = 0; p < 4; p++)
#pragma unroll
        for (int q = 0; q < 4; q++)
            V[(size_t)(p * 4 + q) * BPQ + vo] = __float2bfloat16(vm[p][q]);
}

// ---------------------------------------------------------------------------
// Kernel 3: fused GEMM + output transform — m201-style 2-barrier phase slots.
// Block [128 kout x 128 bij], 512 thr = 8 waves (2m x 4n), wave tile 64x32.
// BK=64, 32 iterations x 2 phases (kk=0,1). Per phase per wave:
//   {2 gload16 (1/2 of stage t+3) ; 6 ds_read_b128 ; sched_barrier ;
//    [ph1: counted vmcnt(8)] ; s_barrier ; lgkmcnt(0)+sched_barrier ;
//    setprio1 ; 8 MFMA ; setprio0 ; s_barrier}
// 4 LDS buffers (128 KB), depth 3; vmcnt tail 8 -> 4 -> 0. Contiguous
// staging + XOR granule swizzle (conflict-free reads, coalesced loads).
// Per-pq fold into 4 register Y-planes (wave-uniform scalar weights).
// ---------------------------------------------------------------------------
#define ABYTES 16384
#define BUFSZ  32768

__global__ __launch_bounds__(512, 2) void wg_gemm7(const __hip_bfloat16* __restrict__ U,
                                                   const __hip_bfloat16* __restrict__ V,
                                                   const float* __restrict__ bias,
                                                   float* __restrict__ out) {
    __shared__ char lds[4 * BUFSZ];      // 128 KB

    // bijective XCD swizzle (256 % 8 == 0): 32 consecutive wg per XCD
    int orig = blockIdx.x;
    int wg   = (orig & 7) * 32 + (orig >> 3);
    const int mt = wg & 1, nt = wg >> 1;
    const int m0 = mt * 128, n0 = nt * 128;

    const int tid  = threadIdx.x;
    const int lane = tid & 63;
    const int wave = tid >> 6;
    const int wm = wave >> 2, wn = wave & 3;

    // staging: chunk c holds tile granule (row R=c>>3, gran G=(c&7)^(R&7))
    const __hip_bfloat16* pa[2];
    const __hip_bfloat16* pb[2];
    int ldsA[2], ldsB[2];
#pragma unroll
    for (int ch = 0; ch < 2; ch++) {
        int c = ch * 512 + tid;
        int R = c >> 3;
        int G = (c & 7) ^ (R & 7);
        pa[ch] = U + (m0 + R) * CIN + G * 8;
        pb[ch] = V + (size_t)(n0 + R) * CIN + G * 8;
        ldsA[ch] = c * 16;
        ldsB[ch] = ABYTES + c * 16;
    }

    // ds_read offsets: row r, k-granule g -> byte r*128 + ((g ^ (r&7))<<4)
    const int la = lane & 15, hq = lane >> 4, l7 = lane & 7;
    int aoff[2], boff[2];
#pragma unroll
    for (int kk = 0; kk < 2; kk++) {
        int g = (kk * 4 + hq) ^ l7;
        aoff[kk] = (wm * 64 + la) * 128 + (g << 4);
        boff[kk] = ABYTES + (wn * 32 + la) * 128 + (g << 4);
    }

    f32x4 yac[2][2][4][2];               // [x][y][mi][nj]
#pragma unroll
    for (int x = 0; x < 2; x++)
#pragma unroll
        for (int y = 0; y < 2; y++)
#pragma unroll
            for (int mi = 0; mi < 4; mi++)
#pragma unroll
                for (int nj = 0; nj < 2; nj++) yac[x][y][mi][nj] = (f32x4){0.f, 0.f, 0.f, 0.f};
    f32x4 mac[4][2];
    const f32x4 fz = (f32x4){0.f, 0.f, 0.f, 0.f};

    // one 2-barrier phase slot (m201 template shape)
    auto ph = [&](int t, int kk, bool do_stage, bool init, int vmc) {
        if (do_stage) {                  // half of stage t+3
            const int ts = t + 3;
            char* sb = lds + (ts & 3) * BUFSZ;
            const int pq = ts >> 1, kb = (ts & 1) * 64;
            gload16(pa[kk] + pq * APQ + kb, sb + ldsA[kk]);
            gload16(pb[kk] + (size_t)pq * BPQ + kb, sb + ldsB[kk]);
        }
        const char* rb = lds + (t & 3) * BUFSZ;
        bf16x8 av[4], bw[2];
#pragma unroll
        for (int mi = 0; mi < 4; mi++)
            av[mi] = *reinterpret_cast<const bf16x8*>(rb + aoff[kk] + mi * 2048);
#pragma unroll
        for (int nj = 0; nj < 2; nj++)
            bw[nj] = *reinterpret_cast<const bf16x8*>(rb + boff[kk] + nj * 2048);
        __builtin_amdgcn_sched_barrier(0);       // reads stay before barrier
        if (vmc == 8)      asm volatile("s_waitcnt vmcnt(8)");
        else if (vmc == 4) asm volatile("s_waitcnt vmcnt(4)");
        else if (vmc == 0) asm volatile("s_waitcnt vmcnt(0)");
        __builtin_amdgcn_s_barrier();
        asm volatile("s_waitcnt lgkmcnt(0)");
        __builtin_amdgcn_sched_barrier(0);       // rule 18: pin MFMA after wait
        __builtin_amdgcn_s_setprio(1);
#pragma unroll
        for (int mi = 0; mi < 4; mi++)
#pragma unroll
            for (int nj = 0; nj < 2; nj++)
                mac[mi][nj] = __builtin_amdgcn_mfma_f32_16x16x32_bf16(
                    av[mi], bw[nj], init ? fz : mac[mi][nj], 0, 0, 0);
        __builtin_amdgcn_s_setprio(0);
        __builtin_amdgcn_sched_barrier(0);
        __builtin_amdgcn_s_barrier();
    };

    auto fold = [&](int pq) {            // M[pq] -> 4 Y planes (uniform weights)
        const int p = pq >> 2, q = pq & 3;
        const float w0p = (p == 3) ? 0.f : 1.f;
        const float w1p = (p == 0) ? 0.f : ((p == 1) ? 1.f : -1.f);
        const float w0q = (q == 3) ? 0.f : 1.f;
        const float w1q = (q == 0) ? 0.f : ((q == 1) ? 1.f : -1.f);
#pragma unroll
        for (int mi = 0; mi < 4; mi++)
#pragma unroll
            for (int nj = 0; nj < 2; nj++) {
                f32x4 m  = mac[mi][nj];
                f32x4 q0 = w0q * m, q1 = w1q * m;
                yac[0][0][mi][nj] += w0p * q0;
                yac[0][1][mi][nj] += w0p * q1;
                yac[1][0][mi][nj] += w1p * q0;
                yac[1][1][mi][nj] += w1p * q1;
            }
    };

    auto stage_full = [&](int t) {
        char* sb = lds + (t & 3) * BUFSZ;
        const int pq = t >> 1, kb = (t & 1) * 64;
#pragma unroll
        for (int ch = 0; ch < 2; ch++) {
            gload16(pa[ch] + pq * APQ + kb, sb + ldsA[ch]);
            gload16(pb[ch] + (size_t)pq * BPQ + kb, sb + ldsB[ch]);
        }
    };

    stage_full(0); stage_full(1); stage_full(2);
    asm volatile("s_waitcnt vmcnt(8)");          // drain stage 0 only
    __builtin_amdgcn_s_barrier();

    for (int t = 0; t < 28; t += 2) {            // rolled: small I-footprint
        ph(t,     0, true, true,  -1);
        ph(t,     1, true, false,  8);
        ph(t + 1, 0, true, false, -1);
        ph(t + 1, 1, true, false,  8);
        fold(t >> 1);
    }
    // peeled tail: stages exhausted, drain 8 -> 4 -> 0
    ph(28, 0, true,  true,  -1); ph(28, 1, true,  false, 8);
    ph(29, 0, false, false, -1); ph(29, 1, false, false, 4); fold(14);
    ph(30, 0, false, true,  -1); ph(30, 1, false, false, 0);
    ph(31, 0, false, false, -1); ph(31, 1, false, false, -1); fold(15);

    // ---- writeout: D frag: col(bij)=lane&15, row(kout)=(lane>>4)*4+r ----
    const int lr = lane & 15, rg = lane >> 4;
#pragma unroll
    for (int mi = 0; mi < 4; mi++) {
#pragma unroll
        for (int r = 0; r < 4; r++) {
            const int kout = m0 + wm * 64 + mi * 16 + rg * 4 + r;
            const float bvv = bias[kout];
#pragma unroll
            for (int nj = 0; nj < 2; nj++) {
                const int bij = n0 + wn * 32 + nj * 16 + lr;
                const int bb = bij >> 10, ti = (bij >> 5) & 31, tj = bij & 31;
                float* op = out + (((size_t)bb * COUT + kout) * HH + 2 * ti) * WW + 2 * tj;
                *reinterpret_cast<float2*>(op) =
                    make_float2(yac[0][0][mi][nj][r] + bvv, yac[0][1][mi][nj][r] + bvv);
                *reinterpret_cast<float2*>(op + WW) =
                    make_float2(yac[1][0][mi][nj][r] + bvv, yac[1][1][mi][nj][r] + bvv);
            }
        }
    }
}

// ---------------------------------------------------------------------------
extern "C" void kernel_launch(void* const* d_in, const int* in_sizes, int n_in,
                              void* d_out, int out_size, void* d_ws, size_t ws_size,
                              hipStream_t stream) {
    const float* X    = (const float*)d_in[0];
    const float* w    = (const float*)d_in[1];
    const float* bias = (const float*)d_in[2];
    float* out        = (float*)d_out;

    __hip_bfloat16* U = (__hip_bfloat16*)d_ws;                       // 1 MB
    __hip_bfloat16* V = (__hip_bfloat16*)((char*)d_ws + (1u << 20)); // 64 MB

    wg_wtrans<<<(COUT * CIN + 255) / 256, 256, 0, stream>>>(w, U);
    wg_itrans<<<dim3(CIN / 32, TH, BATCH), 1024, 0, stream>>>(X, V);
    wg_gemm7<<<(COUT / 128) * (NT / 128), 512, 0, stream>>>(U, V, bias, out);
}